// Round 5
// baseline (603.877 us; speedup 1.0000x reference)
//
#include <hip/hip_runtime.h>
#include <math.h>

// GraphConvolution: out = segment_sum(edge_val * x[edge_col], edge_row) + x_0 + bias
// (Cayley transform in the reference is exactly identity => support == x.)
//
// Round 17: direct ds_add_f32 accumulation -- delete the bucket stage.
//   R16 landed at 138.4; spmm left top-5 (fills at 42 us dominate; ~20 tiny
//   harness reset dispatches + fill are a fixed ~45-50 us tax). spmm is the
//   top controllable item. Its bucket stage did aggregation twice (LDS
//   cursor scatter + 16KB zero + broadcast re-read with 262K bank conflicts
//   + row-imbalanced batches). CDNA has native ds_add_f32, so each edge now
//   directly does acc[row][lane] += val * x16[col][lane]:
//   - per-wave: 16 cells preloaded as 4 coalesced 512-B reads; entry
//     metadata broadcast via v_readlane (1 instr/wave); 8 gathers in flight.
//   - LDS = acc 16 KB only; no cursors, no C_ROW overflow, edge-balanced.
//   - ~48 VGPR, 4 blocks/CU: all 1024 blocks co-resident in one shot.
//   - spmm overflow path gone -> drain handles build regions only.
//   Build (R16 structure) unchanged this round.

#define DFEAT 64
#define RPB   64            // rows per partition
#define NPART_MAX 1024
#define BBLK  128           // build blocks == cells per partition
#define BUILD_T 1024
#define CONV_BLK 256
#define CAPC  15            // entries per cell (slot 0 holds the count)
#define CELL_I2 16          // int2 per cell (128 B)
#define SPMM_T 512          // spmm block size (8 waves)

// ---------------- Round-17 path (N <= 65536, N % 64 == 0) ------------------

__global__ void zero_ints_kernel(int* __restrict__ p, int n) {
    int i = blockIdx.x * blockDim.x + threadIdx.x;
    if (i < n) p[i] = 0;
}

// blocks [0, BBLK): LDS-staged partition build (dynamic LDS)
// blocks [BBLK, BBLK+CONV_BLK): RTN f32 -> bf16 conversion of x
__global__ __launch_bounds__(BUILD_T) void build_conv_kernel(
        const int* __restrict__ edge_row,
        const int* __restrict__ edge_col,
        const float* __restrict__ edge_val,
        const float* __restrict__ x,
        unsigned short* __restrict__ x16,
        int2* __restrict__ slists,        // [NP][BBLK][CELL_I2] p-major
        int* __restrict__ ov_cnt,        // [BBLK] (no pre-zero needed)
        int2* __restrict__ ov,           // [BBLK][epb]
        int E, int NP, int epb, int n4) {
    int t = threadIdx.x;

    if (blockIdx.x >= BBLK) {
        // ---- conversion role ----
        int stride = CONV_BLK * BUILD_T;
        for (int i = (blockIdx.x - BBLK) * BUILD_T + t; i < n4; i += stride) {
            float4 v = ((const float4*)x)[i];
            ushort4 o;
            unsigned u;
            u = __float_as_uint(v.x); o.x = (unsigned short)((u + 0x7FFFu + ((u >> 16) & 1u)) >> 16);
            u = __float_as_uint(v.y); o.y = (unsigned short)((u + 0x7FFFu + ((u >> 16) & 1u)) >> 16);
            u = __float_as_uint(v.z); o.z = (unsigned short)((u + 0x7FFFu + ((u >> 16) & 1u)) >> 16);
            u = __float_as_uint(v.w); o.w = (unsigned short)((u + 0x7FFFu + ((u >> 16) & 1u)) >> 16);
            ((ushort4*)x16)[i] = o;       // cached: warms L2/L3 for spmm
        }
        return;
    }

    // ---- build role ----
    extern __shared__ char smem[];
    int2* cell = (int2*)smem;                           // NP * CELL_I2
    int*  cnt  = (int*)(smem + (size_t)NP * 128);       // NP + 1 (ov counter)

    int b = blockIdx.x;
    for (int i = t; i < NP + 1; i += BUILD_T) cnt[i] = 0;
    __syncthreads();

    int base = b * epb;
    int end = base + epb; if (end > E) end = E;

    for (int e = base + t; e < end; e += BUILD_T) {
        int r = edge_row[e];
        int c = edge_col[e];
        float v = edge_val[e];
        int p = r >> 6;
        int2 ent;
        ent.x = (int)(((unsigned)r << 16) | (unsigned)c);
        ent.y = __float_as_int(v);
        int pos = atomicAdd(&cnt[p], 1);          // LDS
        if (pos < CAPC) {
            cell[p * CELL_I2 + 1 + pos] = ent;
        } else {
            int op = atomicAdd(&cnt[NP], 1);      // rare (~2K total)
            ov[(size_t)b * epb + op] = ent;       // op < edges-in-block <= epb
        }
    }
    __syncthreads();
    for (int p = t; p < NP; p += BUILD_T) {
        int cc = cnt[p];
        cell[p * CELL_I2].x = (cc > CAPC) ? CAPC : cc;
    }
    __syncthreads();
    // flush: full 128-B cells; slists p-major => spmm reads 16 KB streams.
    {
        int4* g4 = (int4*)slists;
        const int4* l4 = (const int4*)cell;
        for (int i = t; i < NP * 8; i += BUILD_T) {
            int p = i >> 3, q = i & 7;
            g4[((size_t)p * BBLK + (unsigned)b) * 8 + q] = l4[i];
        }
    }
    if (t == 0) ov_cnt[b] = cnt[NP];
}

// Block per partition: direct ds_add_f32 accumulation, no bucket stage.
__global__ __launch_bounds__(SPMM_T) void spmm_fused_kernel(
        const unsigned short* __restrict__ x16,
        const float* __restrict__ x0,
        const float* __restrict__ bias,
        const int2* __restrict__ slists,
        float* __restrict__ out, int NP) {
    __shared__ float acc[RPB * DFEAT];    // 16 KB
    int p = blockIdx.x;
    int t = threadIdx.x;
    int wave = t >> 6, lane = t & 63;

    for (int i = t; i < RPB * DFEAT; i += SPMM_T) acc[i] = 0.f;

    // wave w owns cells [w*16, w*16+16): preload as 4 coalesced 512-B reads
    const int2* list = slists + (size_t)p * BBLK * CELL_I2;
    int2 m[4];
    #pragma unroll
    for (int i = 0; i < 4; i++)
        m[i] = list[wave * 256 + i * 64 + lane];   // cells w*16+i*4 .. +3
    __syncthreads();

    #pragma unroll
    for (int i = 0; i < 4; i++) {
        #pragma unroll
        for (int q = 0; q < 4; q++) {
            int cnt = __builtin_amdgcn_readlane(m[i].x, q * 16);  // slot0.x
            if (cnt > CAPC) cnt = CAPC;
            for (int j0 = 1; j0 <= cnt; j0 += 8) {
                float xv[8], vv[8];
                int   rw[8];
                #pragma unroll
                for (int k = 0; k < 8; k++) {
                    int j = j0 + k;
                    int ji = q * 16 + ((j <= cnt) ? j : 0);  // clamp->header
                    int ex = __builtin_amdgcn_readlane(m[i].x, ji);
                    int ey = __builtin_amdgcn_readlane(m[i].y, ji);
                    vv[k] = (j <= cnt) ? __int_as_float(ey) : 0.f;
                    rw[k] = (int)(((unsigned)ex >> 16) & (RPB - 1));
                    unsigned short hv =
                        x16[(size_t)((unsigned)ex & 0xFFFFu) * DFEAT + lane];
                    xv[k] = __uint_as_float((unsigned)hv << 16);
                }
                #pragma unroll
                for (int k = 0; k < 8; k++)
                    atomicAdd(&acc[rw[k] * DFEAT + lane], vv[k] * xv[k]);
            }
        }
    }
    __syncthreads();

    float bl = bias[lane];
    for (int r = wave; r < RPB; r += (SPMM_T / 64)) {
        size_t go = (size_t)(p * RPB + r) * DFEAT + lane;
        out[go] = acc[r * DFEAT + lane] + x0[go] + bl;   // coalesced 256 B
    }
}

// Drain build-overflow lists with full-precision f32 x. Runs AFTER spmm.
__global__ void ov_drain_kernel(const float* __restrict__ x,
                                const int* __restrict__ ov_cnt,
                                const int2* __restrict__ ov,
                                float* __restrict__ out, int epb) {
    int wid = (blockIdx.x * blockDim.x + threadIdx.x) >> 6;
    int lane = threadIdx.x & 63;
    int nw = (gridDim.x * blockDim.x) >> 6;
    for (int reg = wid; reg < BBLK; reg += nw) {
        int n = ov_cnt[reg];
        if (n > epb) n = epb;
        for (int k = 0; k < n; k++) {
            int2 pk = ov[(size_t)reg * epb + k];
            unsigned ux = (unsigned)pk.x;
            int r = (int)(ux >> 16);
            int c = (int)(ux & 0xFFFFu);
            float v = __int_as_float(pk.y);
            atomicAdd(&out[(size_t)r * DFEAT + lane],
                      v * x[(size_t)c * DFEAT + lane]);
        }
    }
}

// ---------------- R7 single-phase path (general N; medium ws) ---------------

__global__ void bucket_scatter_kernel(const int* __restrict__ edge_row,
                                      const int* __restrict__ edge_col,
                                      const float* __restrict__ edge_val,
                                      int* __restrict__ cursor,
                                      int2* __restrict__ bucket,
                                      int* __restrict__ ov_cursor,
                                      int* __restrict__ ov_list,
                                      int E, int C) {
    int e = blockIdx.x * blockDim.x + threadIdx.x;
    if (e >= E) return;
    int r = edge_row[e];
    int pos = atomicAdd(&cursor[r], 1);
    if (pos < C) {
        int2 ent;
        ent.x = edge_col[e];
        ent.y = __float_as_int(edge_val[e]);
        bucket[(size_t)r * C + pos] = ent;
    } else {
        int op = atomicAdd(ov_cursor, 1);
        ov_list[op] = e;
    }
}

__global__ __launch_bounds__(256) void spmm_kernel(
        const float* __restrict__ x,
        const float* __restrict__ x0,
        const float* __restrict__ bias,
        const int* __restrict__ counts,
        const int2* __restrict__ bucket,
        float* __restrict__ out, int n, int C) {
    int wid = (blockIdx.x * blockDim.x + threadIdx.x) >> 6;
    int lane = threadIdx.x & 63;
    if (wid >= n) return;
    int cnt = counts[wid];
    if (cnt > C) cnt = C;
    const int2* bk = bucket + (size_t)wid * C;
    float acc = 0.f;
    for (int s0 = 0; s0 < cnt; s0 += 64) {
        int m = cnt - s0; if (m > 64) m = 64;
        int c = 0; float v = 0.f;
        if (lane < m) {
            int2 p = bk[s0 + lane];
            c = p.x;
            v = __int_as_float(p.y);
        }
        for (int j0 = 0; j0 < m; j0 += 8) {
            float xv[8], vv[8];
            #pragma unroll
            for (int k = 0; k < 8; k++) {
                int cj = __builtin_amdgcn_readlane(c, j0 + k);
                int vb = __builtin_amdgcn_readlane(__float_as_int(v), j0 + k);
                vv[k] = __int_as_float(vb);
                xv[k] = x[(size_t)cj * DFEAT + lane];
            }
            #pragma unroll
            for (int k = 0; k < 8; k++)
                acc += vv[k] * xv[k];
        }
    }
    out[(size_t)wid * DFEAT + lane] =
        acc + x0[(size_t)wid * DFEAT + lane] + bias[lane];
}

__global__ void ov_drain_id_kernel(const int* __restrict__ edge_row,
                                   const int* __restrict__ edge_col,
                                   const float* __restrict__ edge_val,
                                   const float* __restrict__ x,
                                   const int* __restrict__ ov_cursor,
                                   const int* __restrict__ ov_list,
                                   float* __restrict__ out, int E) {
    int n = ov_cursor[0];
    if (n > E) n = E;
    int wid = (blockIdx.x * blockDim.x + threadIdx.x) >> 6;
    int lane = threadIdx.x & 63;
    int nw = (gridDim.x * blockDim.x) >> 6;
    for (int k = wid; k < n; k += nw) {
        int e = ov_list[k];
        int r = edge_row[e], c = edge_col[e];
        float v = edge_val[e];
        atomicAdd(&out[(size_t)r * DFEAT + lane],
                  v * x[(size_t)c * DFEAT + lane]);
    }
}

// ---------------- last-resort fallback (round-1 structure) ------------------

__global__ void init_out_kernel(const float* __restrict__ x0,
                                const float* __restrict__ bias,
                                float* __restrict__ out, int n4) {
    int i = blockIdx.x * blockDim.x + threadIdx.x;
    if (i < n4) {
        float4 v = ((const float4*)x0)[i];
        int d = (i * 4) & (DFEAT - 1);
        v.x += bias[d + 0]; v.y += bias[d + 1];
        v.z += bias[d + 2]; v.w += bias[d + 3];
        ((float4*)out)[i] = v;
    }
}

__global__ void edge_scatter_kernel(const float* __restrict__ x,
                                    const float* __restrict__ edge_val,
                                    const int* __restrict__ edge_row,
                                    const int* __restrict__ edge_col,
                                    float* __restrict__ out, int E) {
    int tid = blockIdx.x * blockDim.x + threadIdx.x;
    int wave = tid >> 6, lane = tid & 63;
    int nwaves = (gridDim.x * blockDim.x) >> 6;
    for (int e = wave; e < E; e += nwaves) {
        int row = edge_row[e];
        int col = edge_col[e];
        float val = edge_val[e];
        atomicAdd(&out[row * DFEAT + lane], val * x[col * DFEAT + lane]);
    }
}

extern "C" void kernel_launch(void* const* d_in, const int* in_sizes, int n_in,
                              void* d_out, int out_size, void* d_ws, size_t ws_size,
                              hipStream_t stream) {
    const float* x    = (const float*)d_in[0];
    const float* x0   = (const float*)d_in[1];
    const float* ev   = (const float*)d_in[2];
    // d_in[3] = weight: unused (Cayley == identity)
    const float* bias = (const float*)d_in[4];
    const int*   er   = (const int*)d_in[5];
    const int*   ec   = (const int*)d_in[6];
    float* out = (float*)d_out;

    int E = in_sizes[2];
    int N = out_size / DFEAT;

    auto align256 = [](size_t b) { return (b + 255) & ~size_t(255); };

    // ---- Round-17 path ----
    if (N <= 65536 && N % RPB == 0 && E > 0) {
        int NP = N / RPB;                       // partitions (<= 1024)
        int epb = (E + BBLK - 1) / BBLK;        // 8192 for E=1M

        size_t ovc_b  = align256((size_t)BBLK * 4);
        size_t x16_b  = align256((size_t)N * DFEAT * 2);
        size_t ov_b   = align256((size_t)BBLK * epb * 8);
        size_t sl_b   = align256((size_t)NP * BBLK * CELL_I2 * 8);
        size_t total  = ovc_b + x16_b + ov_b + sl_b;
        size_t smem_b = (size_t)NP * 128 + (size_t)(NP + 1) * 4;

        if (total <= ws_size && smem_b <= 160 * 1024) {
            char* ws = (char*)d_ws;
            int*            ovc    = (int*)ws;
            unsigned short* x16    = (unsigned short*)(ws + ovc_b);
            int2*           ovl    = (int2*)(ws + ovc_b + x16_b);
            int2*           slists = (int2*)(ws + ovc_b + x16_b + ov_b);

            int n4 = N * DFEAT / 4;
            build_conv_kernel<<<BBLK + CONV_BLK, BUILD_T, smem_b, stream>>>(
                er, ec, ev, x, x16, slists, ovc, ovl, E, NP, epb, n4);
            spmm_fused_kernel<<<NP, SPMM_T, 0, stream>>>(
                x16, x0, bias, slists, out, NP);
            ov_drain_kernel<<<64, 256, 0, stream>>>(
                x, ovc, ovl, out, epb);
            return;
        }
    }

    // ---- R7 single-phase path ----
    {
        size_t cur_b = align256((size_t)N * 4);
        size_t ovc_b = 256;
        size_t ov_b  = align256((size_t)E * 4);
        size_t fixed = cur_b + ovc_b + ov_b;
        int C = 0;
        if (ws_size > fixed) {
            long long cmax = (long long)((ws_size - fixed) / ((size_t)N * 8));
            for (int cand : {64, 48, 40, 32, 28, 24})
                if (cmax >= cand) { C = cand; break; }
        }
        if (C >= 24) {
            char* ws = (char*)d_ws;
            int*  cursor  = (int*)ws;
            int*  ovc     = (int*)(ws + cur_b);
            int*  ov_list = (int*)(ws + cur_b + ovc_b);
            int2* bucket  = (int2*)(ws + fixed);

            int nzero = (int)((cur_b + ovc_b) / 4);
            zero_ints_kernel<<<(nzero + 255) / 256, 256, 0, stream>>>(cursor, nzero);
            bucket_scatter_kernel<<<(E + 255) / 256, 256, 0, stream>>>(
                er, ec, ev, cursor, bucket, ovc, ov_list, E, C);
            int blocks = (N * 64 + 255) / 256;
            spmm_kernel<<<blocks, 256, 0, stream>>>(
                x, x0, bias, cursor, bucket, out, N, C);
            ov_drain_id_kernel<<<64, 256, 0, stream>>>(
                er, ec, ev, x, ovc, ov_list, out, E);
            return;
        }
    }

    // ---- last resort: atomic scatter ----
    int n4 = out_size / 4;
    init_out_kernel<<<(n4 + 255) / 256, 256, 0, stream>>>(x0, bias, out, n4);
    edge_scatter_kernel<<<8192, 256, 0, stream>>>(x, ev, er, ec, out, E);
}

// Round 6
// 162.124 us; speedup vs baseline: 3.7248x; 3.7248x over previous
//
#include <hip/hip_runtime.h>
#include <math.h>

// GraphConvolution: out = segment_sum(edge_val * x[edge_col], edge_row) + x_0 + bias
// (Cayley transform in the reference is exactly identity => support == x.)
//
// Round 18: revert R17 (readlane-serialized spmm: 497 us, VALUBusy 5.5% --
//   wave-uniform metadata broadcast chained every gather behind serial SALU
//   readlanes, killing load-level parallelism). Back to R16 structure
//   (138.4 us) with ONE change: spmm gather batch 2x8 -> 2x16 (32 loads in
//   flight per wave; ~1.6x net concurrency at ~4 waves/SIMD). Theory: spmm
//   is gather-latency-bound (R15: 2.5-3 TB/s, VALUBusy 37%).

#define DFEAT 64
#define RPB   64            // rows per partition
#define NPART_MAX 1024
#define BBLK  128           // build blocks == cells per partition
#define BUILD_T 1024
#define CONV_BLK 256
#define CAPC  15            // entries per cell (slot 0 holds the count)
#define CELL_I2 16          // int2 per cell (128 B)
#define C_ROW 32            // per-row LDS bucket capacity in spmm
#define SPMM_T 512          // spmm block size (8 waves)
#define OVS_S 2048          // spmm per-partition overflow capacity (>=128*15)

// ---------------- Round-18 path (N <= 65536, N % 64 == 0) ------------------

__global__ void zero_ints_kernel(int* __restrict__ p, int n) {
    int i = blockIdx.x * blockDim.x + threadIdx.x;
    if (i < n) p[i] = 0;
}

// blocks [0, BBLK): LDS-staged partition build (dynamic LDS)
// blocks [BBLK, BBLK+CONV_BLK): RTN f32 -> bf16 conversion of x
__global__ __launch_bounds__(BUILD_T) void build_conv_kernel(
        const int* __restrict__ edge_row,
        const int* __restrict__ edge_col,
        const float* __restrict__ edge_val,
        const float* __restrict__ x,
        unsigned short* __restrict__ x16,
        int2* __restrict__ slists,        // [NP][BBLK][CELL_I2] p-major
        int* __restrict__ ov_cnt,        // [BBLK + NP] (no pre-zero needed)
        int2* __restrict__ ov,           // build regions: [BBLK][epb]
        int E, int NP, int epb, int n4) {
    int t = threadIdx.x;

    if (blockIdx.x >= BBLK) {
        // ---- conversion role ----
        int stride = CONV_BLK * BUILD_T;
        for (int i = (blockIdx.x - BBLK) * BUILD_T + t; i < n4; i += stride) {
            float4 v = ((const float4*)x)[i];
            ushort4 o;
            unsigned u;
            u = __float_as_uint(v.x); o.x = (unsigned short)((u + 0x7FFFu + ((u >> 16) & 1u)) >> 16);
            u = __float_as_uint(v.y); o.y = (unsigned short)((u + 0x7FFFu + ((u >> 16) & 1u)) >> 16);
            u = __float_as_uint(v.z); o.z = (unsigned short)((u + 0x7FFFu + ((u >> 16) & 1u)) >> 16);
            u = __float_as_uint(v.w); o.w = (unsigned short)((u + 0x7FFFu + ((u >> 16) & 1u)) >> 16);
            ((ushort4*)x16)[i] = o;       // cached: warms L2/L3 for spmm
        }
        return;
    }

    // ---- build role ----
    extern __shared__ char smem[];
    int2* cell = (int2*)smem;                           // NP * CELL_I2
    int*  cnt  = (int*)(smem + (size_t)NP * 128);       // NP + 1 (ov counter)

    int b = blockIdx.x;
    for (int i = t; i < NP + 1; i += BUILD_T) cnt[i] = 0;
    __syncthreads();

    int base = b * epb;
    int end = base + epb; if (end > E) end = E;

    for (int e = base + t; e < end; e += BUILD_T) {
        int r = edge_row[e];
        int c = edge_col[e];
        float v = edge_val[e];
        int p = r >> 6;
        int2 ent;
        ent.x = (int)(((unsigned)r << 16) | (unsigned)c);
        ent.y = __float_as_int(v);
        int pos = atomicAdd(&cnt[p], 1);          // LDS
        if (pos < CAPC) {
            cell[p * CELL_I2 + 1 + pos] = ent;
        } else {
            int op = atomicAdd(&cnt[NP], 1);      // rare (~2K total)
            ov[(size_t)b * epb + op] = ent;       // op < edges-in-block <= epb
        }
    }
    __syncthreads();
    for (int p = t; p < NP; p += BUILD_T) {
        int cc = cnt[p];
        cell[p * CELL_I2].x = (cc > CAPC) ? CAPC : cc;
    }
    __syncthreads();
    // flush: full 128-B cells; slists p-major => spmm reads 16 KB streams.
    {
        int4* g4 = (int4*)slists;
        const int4* l4 = (const int4*)cell;
        for (int i = t; i < NP * 8; i += BUILD_T) {
            int p = i >> 3, q = i & 7;
            g4[((size_t)p * BBLK + (unsigned)b) * 8 + q] = l4[i];
        }
    }
    if (t == 0) ov_cnt[b] = cnt[NP];
}

// Block per partition: contiguous slot scan + 2-row-per-wave register spmm.
__global__ __launch_bounds__(SPMM_T) void spmm_fused_kernel(
        const unsigned short* __restrict__ x16,
        const float* __restrict__ x0,
        const float* __restrict__ bias,
        const int2* __restrict__ slists,
        int* __restrict__ ov_cnt,
        int2* __restrict__ ov,           // spmm regions at BBLK*epb
        float* __restrict__ out, int NP, int epb) {
    __shared__ int2 bkt[RPB * C_ROW];     // 16 KB
    __shared__ int  cur[RPB];
    __shared__ int  ccnt[BBLK];           // 512 B
    __shared__ int  s_ov;
    int p = blockIdx.x;
    int t = threadIdx.x;

    if (t < RPB) cur[t] = 0;
    if (t == SPMM_T - 1) s_ov = 0;
    // zero-init buckets: padded slots (col 0, val 0) contribute nothing
    for (int i = t; i < RPB * C_ROW; i += SPMM_T) bkt[i] = make_int2(0, 0);

    const int2* list = slists + (size_t)p * BBLK * CELL_I2;
    if (t < BBLK)
        ccnt[t] = ((const int*)list)[t * CELL_I2 * 2];   // slot0.x (<= CAPC)
    __syncthreads();

    for (int i = t; i < BBLK * CELL_I2; i += SPMM_T) {
        int b = i >> 4, j = i & 15;
        if (j >= 1 && j <= ccnt[b]) {
            int2 ent = list[i];                  // contiguous, L2-hot line
            int row = (int)(((unsigned)ent.x >> 16) & (RPB - 1));
            int pos = atomicAdd(&cur[row], 1);   // ds_add
            if (pos < C_ROW) {
                bkt[row * C_ROW + pos] = ent;
            } else {
                int op = atomicAdd(&s_ov, 1);    // bounded by 128*15 < OVS_S
                ov[(size_t)BBLK * epb + (size_t)p * OVS_S + op] = ent;
            }
        }
    }
    __syncthreads();
    if (t == 0) ov_cnt[BBLK + p] = s_ov;

    int wave = t >> 6, lane = t & 63;
    float bl = bias[lane];
    for (int g = 0; g < 4; g++) {
        int rA = g * 16 + wave;
        int rB = rA + 8;
        int crA = cur[rA] > C_ROW ? C_ROW : cur[rA];
        int crB = cur[rB] > C_ROW ? C_ROW : cur[rB];
        int mA = (crA + 15) & ~15, mB = (crB + 15) & ~15;
        int m = mA > mB ? mA : mB;               // padded slots are zeros
        const int2* ra = &bkt[rA * C_ROW];
        const int2* rb2 = &bkt[rB * C_ROW];
        float accA = 0.f, accB = 0.f;
        for (int j0 = 0; j0 < m; j0 += 16) {
            float xa[16], va[16], xb[16], vb[16];
            #pragma unroll
            for (int k = 0; k < 16; k++) {       // 32 independent gathers
                int2 ea = ra[j0 + k];
                int2 eb = rb2[j0 + k];
                va[k] = __int_as_float(ea.y);
                vb[k] = __int_as_float(eb.y);
                xa[k] = __uint_as_float((unsigned)
                    x16[(size_t)((unsigned)ea.x & 0xFFFFu) * DFEAT + lane] << 16);
                xb[k] = __uint_as_float((unsigned)
                    x16[(size_t)((unsigned)eb.x & 0xFFFFu) * DFEAT + lane] << 16);
            }
            #pragma unroll
            for (int k = 0; k < 16; k++) {
                accA += va[k] * xa[k];
                accB += vb[k] * xb[k];
            }
        }
        size_t goA = (size_t)(p * RPB + rA) * DFEAT + lane;
        size_t goB = (size_t)(p * RPB + rB) * DFEAT + lane;
        out[goA] = accA + x0[goA] + bl;          // coalesced 256 B row store
        out[goB] = accB + x0[goB] + bl;
    }
}

// Drain per-region overflow lists with full-precision f32 x. Runs AFTER spmm.
__global__ void ov_drain_kernel(const float* __restrict__ x,
                                const int* __restrict__ ov_cnt,
                                const int2* __restrict__ ov,
                                float* __restrict__ out,
                                int NP, int epb) {
    int wid = (blockIdx.x * blockDim.x + threadIdx.x) >> 6;
    int lane = threadIdx.x & 63;
    int nw = (gridDim.x * blockDim.x) >> 6;
    int regions = BBLK + NP;
    for (int reg = wid; reg < regions; reg += nw) {
        int n = ov_cnt[reg];
        size_t rbase;
        int cap;
        if (reg < BBLK) { rbase = (size_t)reg * epb; cap = epb; }
        else {
            rbase = (size_t)BBLK * epb + (size_t)(reg - BBLK) * OVS_S;
            cap = OVS_S;
        }
        if (n > cap) n = cap;
        for (int k = 0; k < n; k++) {
            int2 pk = ov[rbase + k];
            unsigned ux = (unsigned)pk.x;
            int r = (int)(ux >> 16);
            int c = (int)(ux & 0xFFFFu);
            float v = __int_as_float(pk.y);
            atomicAdd(&out[(size_t)r * DFEAT + lane],
                      v * x[(size_t)c * DFEAT + lane]);
        }
    }
}

// ---------------- R7 single-phase path (general N; medium ws) ---------------

__global__ void bucket_scatter_kernel(const int* __restrict__ edge_row,
                                      const int* __restrict__ edge_col,
                                      const float* __restrict__ edge_val,
                                      int* __restrict__ cursor,
                                      int2* __restrict__ bucket,
                                      int* __restrict__ ov_cursor,
                                      int* __restrict__ ov_list,
                                      int E, int C) {
    int e = blockIdx.x * blockDim.x + threadIdx.x;
    if (e >= E) return;
    int r = edge_row[e];
    int pos = atomicAdd(&cursor[r], 1);
    if (pos < C) {
        int2 ent;
        ent.x = edge_col[e];
        ent.y = __float_as_int(edge_val[e]);
        bucket[(size_t)r * C + pos] = ent;
    } else {
        int op = atomicAdd(ov_cursor, 1);
        ov_list[op] = e;
    }
}

__global__ __launch_bounds__(256) void spmm_kernel(
        const float* __restrict__ x,
        const float* __restrict__ x0,
        const float* __restrict__ bias,
        const int* __restrict__ counts,
        const int2* __restrict__ bucket,
        float* __restrict__ out, int n, int C) {
    int wid = (blockIdx.x * blockDim.x + threadIdx.x) >> 6;
    int lane = threadIdx.x & 63;
    if (wid >= n) return;
    int cnt = counts[wid];
    if (cnt > C) cnt = C;
    const int2* bk = bucket + (size_t)wid * C;
    float acc = 0.f;
    for (int s0 = 0; s0 < cnt; s0 += 64) {
        int m = cnt - s0; if (m > 64) m = 64;
        int c = 0; float v = 0.f;
        if (lane < m) {
            int2 p = bk[s0 + lane];
            c = p.x;
            v = __int_as_float(p.y);
        }
        for (int j0 = 0; j0 < m; j0 += 8) {
            float xv[8], vv[8];
            #pragma unroll
            for (int k = 0; k < 8; k++) {
                int cj = __builtin_amdgcn_readlane(c, j0 + k);
                int vb = __builtin_amdgcn_readlane(__float_as_int(v), j0 + k);
                vv[k] = __int_as_float(vb);
                xv[k] = x[(size_t)cj * DFEAT + lane];
            }
            #pragma unroll
            for (int k = 0; k < 8; k++)
                acc += vv[k] * xv[k];
        }
    }
    out[(size_t)wid * DFEAT + lane] =
        acc + x0[(size_t)wid * DFEAT + lane] + bias[lane];
}

__global__ void ov_drain_id_kernel(const int* __restrict__ edge_row,
                                   const int* __restrict__ edge_col,
                                   const float* __restrict__ edge_val,
                                   const float* __restrict__ x,
                                   const int* __restrict__ ov_cursor,
                                   const int* __restrict__ ov_list,
                                   float* __restrict__ out, int E) {
    int n = ov_cursor[0];
    if (n > E) n = E;
    int wid = (blockIdx.x * blockDim.x + threadIdx.x) >> 6;
    int lane = threadIdx.x & 63;
    int nw = (gridDim.x * blockDim.x) >> 6;
    for (int k = wid; k < n; k += nw) {
        int e = ov_list[k];
        int r = edge_row[e], c = edge_col[e];
        float v = edge_val[e];
        atomicAdd(&out[(size_t)r * DFEAT + lane],
                  v * x[(size_t)c * DFEAT + lane]);
    }
}

// ---------------- last-resort fallback (round-1 structure) ------------------

__global__ void init_out_kernel(const float* __restrict__ x0,
                                const float* __restrict__ bias,
                                float* __restrict__ out, int n4) {
    int i = blockIdx.x * blockDim.x + threadIdx.x;
    if (i < n4) {
        float4 v = ((const float4*)x0)[i];
        int d = (i * 4) & (DFEAT - 1);
        v.x += bias[d + 0]; v.y += bias[d + 1];
        v.z += bias[d + 2]; v.w += bias[d + 3];
        ((float4*)out)[i] = v;
    }
}

__global__ void edge_scatter_kernel(const float* __restrict__ x,
                                    const float* __restrict__ edge_val,
                                    const int* __restrict__ edge_row,
                                    const int* __restrict__ edge_col,
                                    float* __restrict__ out, int E) {
    int tid = blockIdx.x * blockDim.x + threadIdx.x;
    int wave = tid >> 6, lane = tid & 63;
    int nwaves = (gridDim.x * blockDim.x) >> 6;
    for (int e = wave; e < E; e += nwaves) {
        int row = edge_row[e];
        int col = edge_col[e];
        float val = edge_val[e];
        atomicAdd(&out[row * DFEAT + lane], val * x[col * DFEAT + lane]);
    }
}

extern "C" void kernel_launch(void* const* d_in, const int* in_sizes, int n_in,
                              void* d_out, int out_size, void* d_ws, size_t ws_size,
                              hipStream_t stream) {
    const float* x    = (const float*)d_in[0];
    const float* x0   = (const float*)d_in[1];
    const float* ev   = (const float*)d_in[2];
    // d_in[3] = weight: unused (Cayley == identity)
    const float* bias = (const float*)d_in[4];
    const int*   er   = (const int*)d_in[5];
    const int*   ec   = (const int*)d_in[6];
    float* out = (float*)d_out;

    int E = in_sizes[2];
    int N = out_size / DFEAT;

    auto align256 = [](size_t b) { return (b + 255) & ~size_t(255); };

    // ---- Round-18 path ----
    if (N <= 65536 && N % RPB == 0 && E > 0) {
        int NP = N / RPB;                       // partitions (<= 1024)
        int epb = (E + BBLK - 1) / BBLK;        // 8192 for E=1M

        size_t ovc_b  = align256((size_t)(BBLK + NP) * 4);
        size_t x16_b  = align256((size_t)N * DFEAT * 2);
        size_t ov_b   = align256(((size_t)BBLK * epb + (size_t)NP * OVS_S) * 8);
        size_t sl_b   = align256((size_t)NP * BBLK * CELL_I2 * 8);
        size_t total  = ovc_b + x16_b + ov_b + sl_b;
        size_t smem_b = (size_t)NP * 128 + (size_t)(NP + 1) * 4;

        if (total <= ws_size && smem_b <= 160 * 1024) {
            char* ws = (char*)d_ws;
            int*            ovc    = (int*)ws;
            unsigned short* x16    = (unsigned short*)(ws + ovc_b);
            int2*           ovl    = (int2*)(ws + ovc_b + x16_b);
            int2*           slists = (int2*)(ws + ovc_b + x16_b + ov_b);

            int n4 = N * DFEAT / 4;
            build_conv_kernel<<<BBLK + CONV_BLK, BUILD_T, smem_b, stream>>>(
                er, ec, ev, x, x16, slists, ovc, ovl, E, NP, epb, n4);
            spmm_fused_kernel<<<NP, SPMM_T, 0, stream>>>(
                x16, x0, bias, slists, ovc, ovl, out, NP, epb);
            ov_drain_kernel<<<256, 256, 0, stream>>>(
                x, ovc, ovl, out, NP, epb);
            return;
        }
    }

    // ---- R7 single-phase path ----
    {
        size_t cur_b = align256((size_t)N * 4);
        size_t ovc_b = 256;
        size_t ov_b  = align256((size_t)E * 4);
        size_t fixed = cur_b + ovc_b + ov_b;
        int C = 0;
        if (ws_size > fixed) {
            long long cmax = (long long)((ws_size - fixed) / ((size_t)N * 8));
            for (int cand : {64, 48, 40, 32, 28, 24})
                if (cmax >= cand) { C = cand; break; }
        }
        if (C >= 24) {
            char* ws = (char*)d_ws;
            int*  cursor  = (int*)ws;
            int*  ovc     = (int*)(ws + cur_b);
            int*  ov_list = (int*)(ws + cur_b + ovc_b);
            int2* bucket  = (int2*)(ws + fixed);

            int nzero = (int)((cur_b + ovc_b) / 4);
            zero_ints_kernel<<<(nzero + 255) / 256, 256, 0, stream>>>(cursor, nzero);
            bucket_scatter_kernel<<<(E + 255) / 256, 256, 0, stream>>>(
                er, ec, ev, cursor, bucket, ovc, ov_list, E, C);
            int blocks = (N * 64 + 255) / 256;
            spmm_kernel<<<blocks, 256, 0, stream>>>(
                x, x0, bias, cursor, bucket, out, N, C);
            ov_drain_id_kernel<<<64, 256, 0, stream>>>(
                er, ec, ev, x, ovc, ov_list, out, E);
            return;
        }
    }

    // ---- last resort: atomic scatter ----
    int n4 = out_size / 4;
    init_out_kernel<<<(n4 + 255) / 256, 256, 0, stream>>>(x0, bias, out, n4);
    edge_scatter_kernel<<<8192, 256, 0, stream>>>(x, ev, er, ec, out, E);
}

// Round 7
// 141.753 us; speedup vs baseline: 4.2601x; 1.1437x over previous
//
#include <hip/hip_runtime.h>
#include <math.h>

// GraphConvolution: out = segment_sum(edge_val * x[edge_col], edge_row) + x_0 + bias
// (Cayley transform in the reference is exactly identity => support == x.)
//
// Round 19: revert R18 (batch-16 spmm: VGPR=40 proves compiler re-rolled the
//   batch -- LESS concurrency, occ 38%, 162 us). Back to exact R16 spmm
//   (best: 138.4 us) plus two mechanism-clear micro-fixes:
//   - x0 register prefetch at kernel entry (addresses known immediately):
//     8 loads complete under the bucket stage instead of serializing in the
//     store tail (~16.7 MB of latency-exposed reads removed from the tail).
//   - bkt row stride 32 -> 33 int2: breaks pos-aligned LDS bank aliasing in
//     the scatter stage (~310 K conflict cycles in R15/R18 counters).
//   Build/conv/drain identical to R16.

#define DFEAT 64
#define RPB   64            // rows per partition
#define NPART_MAX 1024
#define BBLK  128           // build blocks == cells per partition
#define BUILD_T 1024
#define CONV_BLK 256
#define CAPC  15            // entries per cell (slot 0 holds the count)
#define CELL_I2 16          // int2 per cell (128 B)
#define C_ROW 32            // per-row LDS bucket capacity in spmm
#define BSTR  33            // bkt row stride in int2 (+1 pad vs C_ROW)
#define SPMM_T 512          // spmm block size (8 waves)
#define OVS_S 2048          // spmm per-partition overflow capacity (>=128*15)

// ---------------- Round-19 path (N <= 65536, N % 64 == 0) ------------------

__global__ void zero_ints_kernel(int* __restrict__ p, int n) {
    int i = blockIdx.x * blockDim.x + threadIdx.x;
    if (i < n) p[i] = 0;
}

// blocks [0, BBLK): LDS-staged partition build (dynamic LDS)
// blocks [BBLK, BBLK+CONV_BLK): RTN f32 -> bf16 conversion of x
__global__ __launch_bounds__(BUILD_T) void build_conv_kernel(
        const int* __restrict__ edge_row,
        const int* __restrict__ edge_col,
        const float* __restrict__ edge_val,
        const float* __restrict__ x,
        unsigned short* __restrict__ x16,
        int2* __restrict__ slists,        // [NP][BBLK][CELL_I2] p-major
        int* __restrict__ ov_cnt,        // [BBLK + NP] (no pre-zero needed)
        int2* __restrict__ ov,           // build regions: [BBLK][epb]
        int E, int NP, int epb, int n4) {
    int t = threadIdx.x;

    if (blockIdx.x >= BBLK) {
        // ---- conversion role ----
        int stride = CONV_BLK * BUILD_T;
        for (int i = (blockIdx.x - BBLK) * BUILD_T + t; i < n4; i += stride) {
            float4 v = ((const float4*)x)[i];
            ushort4 o;
            unsigned u;
            u = __float_as_uint(v.x); o.x = (unsigned short)((u + 0x7FFFu + ((u >> 16) & 1u)) >> 16);
            u = __float_as_uint(v.y); o.y = (unsigned short)((u + 0x7FFFu + ((u >> 16) & 1u)) >> 16);
            u = __float_as_uint(v.z); o.z = (unsigned short)((u + 0x7FFFu + ((u >> 16) & 1u)) >> 16);
            u = __float_as_uint(v.w); o.w = (unsigned short)((u + 0x7FFFu + ((u >> 16) & 1u)) >> 16);
            ((ushort4*)x16)[i] = o;       // cached: warms L2/L3 for spmm
        }
        return;
    }

    // ---- build role ----
    extern __shared__ char smem[];
    int2* cell = (int2*)smem;                           // NP * CELL_I2
    int*  cnt  = (int*)(smem + (size_t)NP * 128);       // NP + 1 (ov counter)

    int b = blockIdx.x;
    for (int i = t; i < NP + 1; i += BUILD_T) cnt[i] = 0;
    __syncthreads();

    int base = b * epb;
    int end = base + epb; if (end > E) end = E;

    for (int e = base + t; e < end; e += BUILD_T) {
        int r = edge_row[e];
        int c = edge_col[e];
        float v = edge_val[e];
        int p = r >> 6;
        int2 ent;
        ent.x = (int)(((unsigned)r << 16) | (unsigned)c);
        ent.y = __float_as_int(v);
        int pos = atomicAdd(&cnt[p], 1);          // LDS
        if (pos < CAPC) {
            cell[p * CELL_I2 + 1 + pos] = ent;
        } else {
            int op = atomicAdd(&cnt[NP], 1);      // rare (~2K total)
            ov[(size_t)b * epb + op] = ent;       // op < edges-in-block <= epb
        }
    }
    __syncthreads();
    for (int p = t; p < NP; p += BUILD_T) {
        int cc = cnt[p];
        cell[p * CELL_I2].x = (cc > CAPC) ? CAPC : cc;
    }
    __syncthreads();
    // flush: full 128-B cells; slists p-major => spmm reads 16 KB streams.
    {
        int4* g4 = (int4*)slists;
        const int4* l4 = (const int4*)cell;
        for (int i = t; i < NP * 8; i += BUILD_T) {
            int p = i >> 3, q = i & 7;
            g4[((size_t)p * BBLK + (unsigned)b) * 8 + q] = l4[i];
        }
    }
    if (t == 0) ov_cnt[b] = cnt[NP];
}

// Block per partition: contiguous slot scan + 2-row-per-wave register spmm.
__global__ __launch_bounds__(SPMM_T) void spmm_fused_kernel(
        const unsigned short* __restrict__ x16,
        const float* __restrict__ x0,
        const float* __restrict__ bias,
        const int2* __restrict__ slists,
        int* __restrict__ ov_cnt,
        int2* __restrict__ ov,           // spmm regions at BBLK*epb
        float* __restrict__ out, int NP, int epb) {
    __shared__ int2 bkt[RPB * BSTR];      // 16.5 KB (stride-padded)
    __shared__ int  cur[RPB];
    __shared__ int  ccnt[BBLK];           // 512 B
    __shared__ int  s_ov;
    int p = blockIdx.x;
    int t = threadIdx.x;
    int wave = t >> 6, lane = t & 63;

    // ---- prefetch: x0 rows this wave will store + bias (known addresses) --
    float bl = bias[lane];
    float px0[8];
    #pragma unroll
    for (int g = 0; g < 4; g++) {
        size_t goA = (size_t)(p * RPB + g * 16 + wave) * DFEAT + lane;
        px0[g * 2]     = x0[goA];
        px0[g * 2 + 1] = x0[goA + 8 * DFEAT];
    }

    if (t < RPB) cur[t] = 0;
    if (t == SPMM_T - 1) s_ov = 0;
    // zero-init buckets: padded slots (col 0, val 0) contribute nothing
    for (int i = t; i < RPB * BSTR; i += SPMM_T) bkt[i] = make_int2(0, 0);

    const int2* list = slists + (size_t)p * BBLK * CELL_I2;
    if (t < BBLK)
        ccnt[t] = ((const int*)list)[t * CELL_I2 * 2];   // slot0.x (<= CAPC)
    __syncthreads();

    for (int i = t; i < BBLK * CELL_I2; i += SPMM_T) {
        int b = i >> 4, j = i & 15;
        if (j >= 1 && j <= ccnt[b]) {
            int2 ent = list[i];                  // contiguous, L2-hot line
            int row = (int)(((unsigned)ent.x >> 16) & (RPB - 1));
            int pos = atomicAdd(&cur[row], 1);   // ds_add
            if (pos < C_ROW) {
                bkt[row * BSTR + pos] = ent;
            } else {
                int op = atomicAdd(&s_ov, 1);    // bounded by 128*15 < OVS_S
                ov[(size_t)BBLK * epb + (size_t)p * OVS_S + op] = ent;
            }
        }
    }
    __syncthreads();
    if (t == 0) ov_cnt[BBLK + p] = s_ov;

    for (int g = 0; g < 4; g++) {
        int rA = g * 16 + wave;
        int rB = rA + 8;
        int crA = cur[rA] > C_ROW ? C_ROW : cur[rA];
        int crB = cur[rB] > C_ROW ? C_ROW : cur[rB];
        int mA = (crA + 7) & ~7, mB = (crB + 7) & ~7;
        int m = mA > mB ? mA : mB;               // padded slots are zeros
        const int2* ra = &bkt[rA * BSTR];
        const int2* rb2 = &bkt[rB * BSTR];
        float accA = 0.f, accB = 0.f;
        for (int j0 = 0; j0 < m; j0 += 8) {
            float xa[8], va[8], xb[8], vb[8];
            #pragma unroll
            for (int k = 0; k < 8; k++) {        // 16 independent gathers
                int2 ea = ra[j0 + k];
                int2 eb = rb2[j0 + k];
                va[k] = __int_as_float(ea.y);
                vb[k] = __int_as_float(eb.y);
                xa[k] = __uint_as_float((unsigned)
                    x16[(size_t)((unsigned)ea.x & 0xFFFFu) * DFEAT + lane] << 16);
                xb[k] = __uint_as_float((unsigned)
                    x16[(size_t)((unsigned)eb.x & 0xFFFFu) * DFEAT + lane] << 16);
            }
            #pragma unroll
            for (int k = 0; k < 8; k++) {
                accA += va[k] * xa[k];
                accB += vb[k] * xb[k];
            }
        }
        size_t goA = (size_t)(p * RPB + rA) * DFEAT + lane;
        size_t goB = (size_t)(p * RPB + rB) * DFEAT + lane;
        out[goA] = accA + px0[g * 2]     + bl;   // coalesced 256 B row store
        out[goB] = accB + px0[g * 2 + 1] + bl;
    }
}

// Drain per-region overflow lists with full-precision f32 x. Runs AFTER spmm.
__global__ void ov_drain_kernel(const float* __restrict__ x,
                                const int* __restrict__ ov_cnt,
                                const int2* __restrict__ ov,
                                float* __restrict__ out,
                                int NP, int epb) {
    int wid = (blockIdx.x * blockDim.x + threadIdx.x) >> 6;
    int lane = threadIdx.x & 63;
    int nw = (gridDim.x * blockDim.x) >> 6;
    int regions = BBLK + NP;
    for (int reg = wid; reg < regions; reg += nw) {
        int n = ov_cnt[reg];
        size_t rbase;
        int cap;
        if (reg < BBLK) { rbase = (size_t)reg * epb; cap = epb; }
        else {
            rbase = (size_t)BBLK * epb + (size_t)(reg - BBLK) * OVS_S;
            cap = OVS_S;
        }
        if (n > cap) n = cap;
        for (int k = 0; k < n; k++) {
            int2 pk = ov[rbase + k];
            unsigned ux = (unsigned)pk.x;
            int r = (int)(ux >> 16);
            int c = (int)(ux & 0xFFFFu);
            float v = __int_as_float(pk.y);
            atomicAdd(&out[(size_t)r * DFEAT + lane],
                      v * x[(size_t)c * DFEAT + lane]);
        }
    }
}

// ---------------- R7 single-phase path (general N; medium ws) ---------------

__global__ void bucket_scatter_kernel(const int* __restrict__ edge_row,
                                      const int* __restrict__ edge_col,
                                      const float* __restrict__ edge_val,
                                      int* __restrict__ cursor,
                                      int2* __restrict__ bucket,
                                      int* __restrict__ ov_cursor,
                                      int* __restrict__ ov_list,
                                      int E, int C) {
    int e = blockIdx.x * blockDim.x + threadIdx.x;
    if (e >= E) return;
    int r = edge_row[e];
    int pos = atomicAdd(&cursor[r], 1);
    if (pos < C) {
        int2 ent;
        ent.x = edge_col[e];
        ent.y = __float_as_int(edge_val[e]);
        bucket[(size_t)r * C + pos] = ent;
    } else {
        int op = atomicAdd(ov_cursor, 1);
        ov_list[op] = e;
    }
}

__global__ __launch_bounds__(256) void spmm_kernel(
        const float* __restrict__ x,
        const float* __restrict__ x0,
        const float* __restrict__ bias,
        const int* __restrict__ counts,
        const int2* __restrict__ bucket,
        float* __restrict__ out, int n, int C) {
    int wid = (blockIdx.x * blockDim.x + threadIdx.x) >> 6;
    int lane = threadIdx.x & 63;
    if (wid >= n) return;
    int cnt = counts[wid];
    if (cnt > C) cnt = C;
    const int2* bk = bucket + (size_t)wid * C;
    float acc = 0.f;
    for (int s0 = 0; s0 < cnt; s0 += 64) {
        int m = cnt - s0; if (m > 64) m = 64;
        int c = 0; float v = 0.f;
        if (lane < m) {
            int2 p = bk[s0 + lane];
            c = p.x;
            v = __int_as_float(p.y);
        }
        for (int j0 = 0; j0 < m; j0 += 8) {
            float xv[8], vv[8];
            #pragma unroll
            for (int k = 0; k < 8; k++) {
                int cj = __builtin_amdgcn_readlane(c, j0 + k);
                int vb = __builtin_amdgcn_readlane(__float_as_int(v), j0 + k);
                vv[k] = __int_as_float(vb);
                xv[k] = x[(size_t)cj * DFEAT + lane];
            }
            #pragma unroll
            for (int k = 0; k < 8; k++)
                acc += vv[k] * xv[k];
        }
    }
    out[(size_t)wid * DFEAT + lane] =
        acc + x0[(size_t)wid * DFEAT + lane] + bias[lane];
}

__global__ void ov_drain_id_kernel(const int* __restrict__ edge_row,
                                   const int* __restrict__ edge_col,
                                   const float* __restrict__ edge_val,
                                   const float* __restrict__ x,
                                   const int* __restrict__ ov_cursor,
                                   const int* __restrict__ ov_list,
                                   float* __restrict__ out, int E) {
    int n = ov_cursor[0];
    if (n > E) n = E;
    int wid = (blockIdx.x * blockDim.x + threadIdx.x) >> 6;
    int lane = threadIdx.x & 63;
    int nw = (gridDim.x * blockDim.x) >> 6;
    for (int k = wid; k < n; k += nw) {
        int e = ov_list[k];
        int r = edge_row[e], c = edge_col[e];
        float v = edge_val[e];
        atomicAdd(&out[(size_t)r * DFEAT + lane],
                  v * x[(size_t)c * DFEAT + lane]);
    }
}

// ---------------- last-resort fallback (round-1 structure) ------------------

__global__ void init_out_kernel(const float* __restrict__ x0,
                                const float* __restrict__ bias,
                                float* __restrict__ out, int n4) {
    int i = blockIdx.x * blockDim.x + threadIdx.x;
    if (i < n4) {
        float4 v = ((const float4*)x0)[i];
        int d = (i * 4) & (DFEAT - 1);
        v.x += bias[d + 0]; v.y += bias[d + 1];
        v.z += bias[d + 2]; v.w += bias[d + 3];
        ((float4*)out)[i] = v;
    }
}

__global__ void edge_scatter_kernel(const float* __restrict__ x,
                                    const float* __restrict__ edge_val,
                                    const int* __restrict__ edge_row,
                                    const int* __restrict__ edge_col,
                                    float* __restrict__ out, int E) {
    int tid = blockIdx.x * blockDim.x + threadIdx.x;
    int wave = tid >> 6, lane = tid & 63;
    int nwaves = (gridDim.x * blockDim.x) >> 6;
    for (int e = wave; e < E; e += nwaves) {
        int row = edge_row[e];
        int col = edge_col[e];
        float val = edge_val[e];
        atomicAdd(&out[row * DFEAT + lane], val * x[col * DFEAT + lane]);
    }
}

extern "C" void kernel_launch(void* const* d_in, const int* in_sizes, int n_in,
                              void* d_out, int out_size, void* d_ws, size_t ws_size,
                              hipStream_t stream) {
    const float* x    = (const float*)d_in[0];
    const float* x0   = (const float*)d_in[1];
    const float* ev   = (const float*)d_in[2];
    // d_in[3] = weight: unused (Cayley == identity)
    const float* bias = (const float*)d_in[4];
    const int*   er   = (const int*)d_in[5];
    const int*   ec   = (const int*)d_in[6];
    float* out = (float*)d_out;

    int E = in_sizes[2];
    int N = out_size / DFEAT;

    auto align256 = [](size_t b) { return (b + 255) & ~size_t(255); };

    // ---- Round-19 path ----
    if (N <= 65536 && N % RPB == 0 && E > 0) {
        int NP = N / RPB;                       // partitions (<= 1024)
        int epb = (E + BBLK - 1) / BBLK;        // 8192 for E=1M

        size_t ovc_b  = align256((size_t)(BBLK + NP) * 4);
        size_t x16_b  = align256((size_t)N * DFEAT * 2);
        size_t ov_b   = align256(((size_t)BBLK * epb + (size_t)NP * OVS_S) * 8);
        size_t sl_b   = align256((size_t)NP * BBLK * CELL_I2 * 8);
        size_t total  = ovc_b + x16_b + ov_b + sl_b;
        size_t smem_b = (size_t)NP * 128 + (size_t)(NP + 1) * 4;

        if (total <= ws_size && smem_b <= 160 * 1024) {
            char* ws = (char*)d_ws;
            int*            ovc    = (int*)ws;
            unsigned short* x16    = (unsigned short*)(ws + ovc_b);
            int2*           ovl    = (int2*)(ws + ovc_b + x16_b);
            int2*           slists = (int2*)(ws + ovc_b + x16_b + ov_b);

            int n4 = N * DFEAT / 4;
            build_conv_kernel<<<BBLK + CONV_BLK, BUILD_T, smem_b, stream>>>(
                er, ec, ev, x, x16, slists, ovc, ovl, E, NP, epb, n4);
            spmm_fused_kernel<<<NP, SPMM_T, 0, stream>>>(
                x16, x0, bias, slists, ovc, ovl, out, NP, epb);
            ov_drain_kernel<<<256, 256, 0, stream>>>(
                x, ovc, ovl, out, NP, epb);
            return;
        }
    }

    // ---- R7 single-phase path ----
    {
        size_t cur_b = align256((size_t)N * 4);
        size_t ovc_b = 256;
        size_t ov_b  = align256((size_t)E * 4);
        size_t fixed = cur_b + ovc_b + ov_b;
        int C = 0;
        if (ws_size > fixed) {
            long long cmax = (long long)((ws_size - fixed) / ((size_t)N * 8));
            for (int cand : {64, 48, 40, 32, 28, 24})
                if (cmax >= cand) { C = cand; break; }
        }
        if (C >= 24) {
            char* ws = (char*)d_ws;
            int*  cursor  = (int*)ws;
            int*  ovc     = (int*)(ws + cur_b);
            int*  ov_list = (int*)(ws + cur_b + ovc_b);
            int2* bucket  = (int2*)(ws + fixed);

            int nzero = (int)((cur_b + ovc_b) / 4);
            zero_ints_kernel<<<(nzero + 255) / 256, 256, 0, stream>>>(cursor, nzero);
            bucket_scatter_kernel<<<(E + 255) / 256, 256, 0, stream>>>(
                er, ec, ev, cursor, bucket, ovc, ov_list, E, C);
            int blocks = (N * 64 + 255) / 256;
            spmm_kernel<<<blocks, 256, 0, stream>>>(
                x, x0, bias, cursor, bucket, out, N, C);
            ov_drain_id_kernel<<<64, 256, 0, stream>>>(
                er, ec, ev, x, ovc, ov_list, out, E);
            return;
        }
    }

    // ---- last resort: atomic scatter ----
    int n4 = out_size / 4;
    init_out_kernel<<<(n4 + 255) / 256, 256, 0, stream>>>(x0, bias, out, n4);
    edge_scatter_kernel<<<8192, 256, 0, stream>>>(x, ev, er, ec, out, E);
}

// Round 8
// 141.656 us; speedup vs baseline: 4.2630x; 1.0007x over previous
//
#include <hip/hip_runtime.h>
#include <math.h>

// GraphConvolution: out = segment_sum(edge_val * x[edge_col], edge_row) + x_0 + bias
// (Cayley transform in the reference is exactly identity => support == x.)
//
// Round 20: exact revert to R16 (best measured: 138.4 us).
//   R17 (readlane spmm): 497 us. R18 (batch-16): 162 us. R19 (x0 prefetch +
//   bkt pad): 141.8 us. All three restructures of the R16 spmm lost or tied
//   -- the simple 2-row/wave batch-8 schedule is the local optimum; the
//   compiler schedules it better than any hand variant. Locking R16 back in:
//   - build: 128 blocks x 1024 thr, LDS cells (count + 15 entries, 128 B),
//     p-major slist flush as full lines; conv role fused as extra blocks.
//   - spmm: per-partition slot scan -> LDS row buckets -> 2 rows/wave,
//     batch-8 gathers from bf16 x16; fused out = acc + x0 + bias.
//   - drain: exact f32 correction for all overflow entries.
//   Ledger: fill tax 42 us + ~20 harness resets ~35 us + kernels ~50 us.
//   Remaining theoretical headroom (~12-15 us) sits behind the random-gather
//   latency wall that defeated R13/14/17/18/19.

#define DFEAT 64
#define RPB   64            // rows per partition
#define NPART_MAX 1024
#define BBLK  128           // build blocks == cells per partition
#define BUILD_T 1024
#define CONV_BLK 256
#define CAPC  15            // entries per cell (slot 0 holds the count)
#define CELL_I2 16          // int2 per cell (128 B)
#define C_ROW 32            // per-row LDS bucket capacity in spmm
#define SPMM_T 512          // spmm block size (8 waves)
#define OVS_S 2048          // spmm per-partition overflow capacity (>=128*15)

// ---------------- Round-20 path (N <= 65536, N % 64 == 0) ------------------

__global__ void zero_ints_kernel(int* __restrict__ p, int n) {
    int i = blockIdx.x * blockDim.x + threadIdx.x;
    if (i < n) p[i] = 0;
}

// blocks [0, BBLK): LDS-staged partition build (dynamic LDS)
// blocks [BBLK, BBLK+CONV_BLK): RTN f32 -> bf16 conversion of x
__global__ __launch_bounds__(BUILD_T) void build_conv_kernel(
        const int* __restrict__ edge_row,
        const int* __restrict__ edge_col,
        const float* __restrict__ edge_val,
        const float* __restrict__ x,
        unsigned short* __restrict__ x16,
        int2* __restrict__ slists,        // [NP][BBLK][CELL_I2] p-major
        int* __restrict__ ov_cnt,        // [BBLK + NP] (no pre-zero needed)
        int2* __restrict__ ov,           // build regions: [BBLK][epb]
        int E, int NP, int epb, int n4) {
    int t = threadIdx.x;

    if (blockIdx.x >= BBLK) {
        // ---- conversion role ----
        int stride = CONV_BLK * BUILD_T;
        for (int i = (blockIdx.x - BBLK) * BUILD_T + t; i < n4; i += stride) {
            float4 v = ((const float4*)x)[i];
            ushort4 o;
            unsigned u;
            u = __float_as_uint(v.x); o.x = (unsigned short)((u + 0x7FFFu + ((u >> 16) & 1u)) >> 16);
            u = __float_as_uint(v.y); o.y = (unsigned short)((u + 0x7FFFu + ((u >> 16) & 1u)) >> 16);
            u = __float_as_uint(v.z); o.z = (unsigned short)((u + 0x7FFFu + ((u >> 16) & 1u)) >> 16);
            u = __float_as_uint(v.w); o.w = (unsigned short)((u + 0x7FFFu + ((u >> 16) & 1u)) >> 16);
            ((ushort4*)x16)[i] = o;       // cached: warms L2/L3 for spmm
        }
        return;
    }

    // ---- build role ----
    extern __shared__ char smem[];
    int2* cell = (int2*)smem;                           // NP * CELL_I2
    int*  cnt  = (int*)(smem + (size_t)NP * 128);       // NP + 1 (ov counter)

    int b = blockIdx.x;
    for (int i = t; i < NP + 1; i += BUILD_T) cnt[i] = 0;
    __syncthreads();

    int base = b * epb;
    int end = base + epb; if (end > E) end = E;

    for (int e = base + t; e < end; e += BUILD_T) {
        int r = edge_row[e];
        int c = edge_col[e];
        float v = edge_val[e];
        int p = r >> 6;
        int2 ent;
        ent.x = (int)(((unsigned)r << 16) | (unsigned)c);
        ent.y = __float_as_int(v);
        int pos = atomicAdd(&cnt[p], 1);          // LDS
        if (pos < CAPC) {
            cell[p * CELL_I2 + 1 + pos] = ent;
        } else {
            int op = atomicAdd(&cnt[NP], 1);      // rare (~2K total)
            ov[(size_t)b * epb + op] = ent;       // op < edges-in-block <= epb
        }
    }
    __syncthreads();
    for (int p = t; p < NP; p += BUILD_T) {
        int cc = cnt[p];
        cell[p * CELL_I2].x = (cc > CAPC) ? CAPC : cc;
    }
    __syncthreads();
    // flush: full 128-B cells; slists p-major => spmm reads 16 KB streams.
    {
        int4* g4 = (int4*)slists;
        const int4* l4 = (const int4*)cell;
        for (int i = t; i < NP * 8; i += BUILD_T) {
            int p = i >> 3, q = i & 7;
            g4[((size_t)p * BBLK + (unsigned)b) * 8 + q] = l4[i];
        }
    }
    if (t == 0) ov_cnt[b] = cnt[NP];
}

// Block per partition: contiguous slot scan + 2-row-per-wave register spmm.
__global__ __launch_bounds__(SPMM_T) void spmm_fused_kernel(
        const unsigned short* __restrict__ x16,
        const float* __restrict__ x0,
        const float* __restrict__ bias,
        const int2* __restrict__ slists,
        int* __restrict__ ov_cnt,
        int2* __restrict__ ov,           // spmm regions at BBLK*epb
        float* __restrict__ out, int NP, int epb) {
    __shared__ int2 bkt[RPB * C_ROW];     // 16 KB
    __shared__ int  cur[RPB];
    __shared__ int  ccnt[BBLK];           // 512 B
    __shared__ int  s_ov;
    int p = blockIdx.x;
    int t = threadIdx.x;

    if (t < RPB) cur[t] = 0;
    if (t == SPMM_T - 1) s_ov = 0;
    // zero-init buckets: padded slots (col 0, val 0) contribute nothing
    for (int i = t; i < RPB * C_ROW; i += SPMM_T) bkt[i] = make_int2(0, 0);

    const int2* list = slists + (size_t)p * BBLK * CELL_I2;
    if (t < BBLK)
        ccnt[t] = ((const int*)list)[t * CELL_I2 * 2];   // slot0.x (<= CAPC)
    __syncthreads();

    for (int i = t; i < BBLK * CELL_I2; i += SPMM_T) {
        int b = i >> 4, j = i & 15;
        if (j >= 1 && j <= ccnt[b]) {
            int2 ent = list[i];                  // contiguous, L2-hot line
            int row = (int)(((unsigned)ent.x >> 16) & (RPB - 1));
            int pos = atomicAdd(&cur[row], 1);   // ds_add
            if (pos < C_ROW) {
                bkt[row * C_ROW + pos] = ent;
            } else {
                int op = atomicAdd(&s_ov, 1);    // bounded by 128*15 < OVS_S
                ov[(size_t)BBLK * epb + (size_t)p * OVS_S + op] = ent;
            }
        }
    }
    __syncthreads();
    if (t == 0) ov_cnt[BBLK + p] = s_ov;

    int wave = t >> 6, lane = t & 63;
    float bl = bias[lane];
    for (int g = 0; g < 4; g++) {
        int rA = g * 16 + wave;
        int rB = rA + 8;
        int crA = cur[rA] > C_ROW ? C_ROW : cur[rA];
        int crB = cur[rB] > C_ROW ? C_ROW : cur[rB];
        int mA = (crA + 7) & ~7, mB = (crB + 7) & ~7;
        int m = mA > mB ? mA : mB;               // padded slots are zeros
        const int2* ra = &bkt[rA * C_ROW];
        const int2* rb2 = &bkt[rB * C_ROW];
        float accA = 0.f, accB = 0.f;
        for (int j0 = 0; j0 < m; j0 += 8) {
            float xa[8], va[8], xb[8], vb[8];
            #pragma unroll
            for (int k = 0; k < 8; k++) {        // 16 independent gathers
                int2 ea = ra[j0 + k];
                int2 eb = rb2[j0 + k];
                va[k] = __int_as_float(ea.y);
                vb[k] = __int_as_float(eb.y);
                xa[k] = __uint_as_float((unsigned)
                    x16[(size_t)((unsigned)ea.x & 0xFFFFu) * DFEAT + lane] << 16);
                xb[k] = __uint_as_float((unsigned)
                    x16[(size_t)((unsigned)eb.x & 0xFFFFu) * DFEAT + lane] << 16);
            }
            #pragma unroll
            for (int k = 0; k < 8; k++) {
                accA += va[k] * xa[k];
                accB += vb[k] * xb[k];
            }
        }
        size_t goA = (size_t)(p * RPB + rA) * DFEAT + lane;
        size_t goB = (size_t)(p * RPB + rB) * DFEAT + lane;
        out[goA] = accA + x0[goA] + bl;          // coalesced 256 B row store
        out[goB] = accB + x0[goB] + bl;
    }
}

// Drain per-region overflow lists with full-precision f32 x. Runs AFTER spmm.
__global__ void ov_drain_kernel(const float* __restrict__ x,
                                const int* __restrict__ ov_cnt,
                                const int2* __restrict__ ov,
                                float* __restrict__ out,
                                int NP, int epb) {
    int wid = (blockIdx.x * blockDim.x + threadIdx.x) >> 6;
    int lane = threadIdx.x & 63;
    int nw = (gridDim.x * blockDim.x) >> 6;
    int regions = BBLK + NP;
    for (int reg = wid; reg < regions; reg += nw) {
        int n = ov_cnt[reg];
        size_t rbase;
        int cap;
        if (reg < BBLK) { rbase = (size_t)reg * epb; cap = epb; }
        else {
            rbase = (size_t)BBLK * epb + (size_t)(reg - BBLK) * OVS_S;
            cap = OVS_S;
        }
        if (n > cap) n = cap;
        for (int k = 0; k < n; k++) {
            int2 pk = ov[rbase + k];
            unsigned ux = (unsigned)pk.x;
            int r = (int)(ux >> 16);
            int c = (int)(ux & 0xFFFFu);
            float v = __int_as_float(pk.y);
            atomicAdd(&out[(size_t)r * DFEAT + lane],
                      v * x[(size_t)c * DFEAT + lane]);
        }
    }
}

// ---------------- R7 single-phase path (general N; medium ws) ---------------

__global__ void bucket_scatter_kernel(const int* __restrict__ edge_row,
                                      const int* __restrict__ edge_col,
                                      const float* __restrict__ edge_val,
                                      int* __restrict__ cursor,
                                      int2* __restrict__ bucket,
                                      int* __restrict__ ov_cursor,
                                      int* __restrict__ ov_list,
                                      int E, int C) {
    int e = blockIdx.x * blockDim.x + threadIdx.x;
    if (e >= E) return;
    int r = edge_row[e];
    int pos = atomicAdd(&cursor[r], 1);
    if (pos < C) {
        int2 ent;
        ent.x = edge_col[e];
        ent.y = __float_as_int(edge_val[e]);
        bucket[(size_t)r * C + pos] = ent;
    } else {
        int op = atomicAdd(ov_cursor, 1);
        ov_list[op] = e;
    }
}

__global__ __launch_bounds__(256) void spmm_kernel(
        const float* __restrict__ x,
        const float* __restrict__ x0,
        const float* __restrict__ bias,
        const int* __restrict__ counts,
        const int2* __restrict__ bucket,
        float* __restrict__ out, int n, int C) {
    int wid = (blockIdx.x * blockDim.x + threadIdx.x) >> 6;
    int lane = threadIdx.x & 63;
    if (wid >= n) return;
    int cnt = counts[wid];
    if (cnt > C) cnt = C;
    const int2* bk = bucket + (size_t)wid * C;
    float acc = 0.f;
    for (int s0 = 0; s0 < cnt; s0 += 64) {
        int m = cnt - s0; if (m > 64) m = 64;
        int c = 0; float v = 0.f;
        if (lane < m) {
            int2 p = bk[s0 + lane];
            c = p.x;
            v = __int_as_float(p.y);
        }
        for (int j0 = 0; j0 < m; j0 += 8) {
            float xv[8], vv[8];
            #pragma unroll
            for (int k = 0; k < 8; k++) {
                int cj = __builtin_amdgcn_readlane(c, j0 + k);
                int vb = __builtin_amdgcn_readlane(__float_as_int(v), j0 + k);
                vv[k] = __int_as_float(vb);
                xv[k] = x[(size_t)cj * DFEAT + lane];
            }
            #pragma unroll
            for (int k = 0; k < 8; k++)
                acc += vv[k] * xv[k];
        }
    }
    out[(size_t)wid * DFEAT + lane] =
        acc + x0[(size_t)wid * DFEAT + lane] + bias[lane];
}

__global__ void ov_drain_id_kernel(const int* __restrict__ edge_row,
                                   const int* __restrict__ edge_col,
                                   const float* __restrict__ edge_val,
                                   const float* __restrict__ x,
                                   const int* __restrict__ ov_cursor,
                                   const int* __restrict__ ov_list,
                                   float* __restrict__ out, int E) {
    int n = ov_cursor[0];
    if (n > E) n = E;
    int wid = (blockIdx.x * blockDim.x + threadIdx.x) >> 6;
    int lane = threadIdx.x & 63;
    int nw = (gridDim.x * blockDim.x) >> 6;
    for (int k = wid; k < n; k += nw) {
        int e = ov_list[k];
        int r = edge_row[e], c = edge_col[e];
        float v = edge_val[e];
        atomicAdd(&out[(size_t)r * DFEAT + lane],
                  v * x[(size_t)c * DFEAT + lane]);
    }
}

// ---------------- last-resort fallback (round-1 structure) ------------------

__global__ void init_out_kernel(const float* __restrict__ x0,
                                const float* __restrict__ bias,
                                float* __restrict__ out, int n4) {
    int i = blockIdx.x * blockDim.x + threadIdx.x;
    if (i < n4) {
        float4 v = ((const float4*)x0)[i];
        int d = (i * 4) & (DFEAT - 1);
        v.x += bias[d + 0]; v.y += bias[d + 1];
        v.z += bias[d + 2]; v.w += bias[d + 3];
        ((float4*)out)[i] = v;
    }
}

__global__ void edge_scatter_kernel(const float* __restrict__ x,
                                    const float* __restrict__ edge_val,
                                    const int* __restrict__ edge_row,
                                    const int* __restrict__ edge_col,
                                    float* __restrict__ out, int E) {
    int tid = blockIdx.x * blockDim.x + threadIdx.x;
    int wave = tid >> 6, lane = tid & 63;
    int nwaves = (gridDim.x * blockDim.x) >> 6;
    for (int e = wave; e < E; e += nwaves) {
        int row = edge_row[e];
        int col = edge_col[e];
        float val = edge_val[e];
        atomicAdd(&out[row * DFEAT + lane], val * x[col * DFEAT + lane]);
    }
}

extern "C" void kernel_launch(void* const* d_in, const int* in_sizes, int n_in,
                              void* d_out, int out_size, void* d_ws, size_t ws_size,
                              hipStream_t stream) {
    const float* x    = (const float*)d_in[0];
    const float* x0   = (const float*)d_in[1];
    const float* ev   = (const float*)d_in[2];
    // d_in[3] = weight: unused (Cayley == identity)
    const float* bias = (const float*)d_in[4];
    const int*   er   = (const int*)d_in[5];
    const int*   ec   = (const int*)d_in[6];
    float* out = (float*)d_out;

    int E = in_sizes[2];
    int N = out_size / DFEAT;

    auto align256 = [](size_t b) { return (b + 255) & ~size_t(255); };

    // ---- Round-20 path ----
    if (N <= 65536 && N % RPB == 0 && E > 0) {
        int NP = N / RPB;                       // partitions (<= 1024)
        int epb = (E + BBLK - 1) / BBLK;        // 8192 for E=1M

        size_t ovc_b  = align256((size_t)(BBLK + NP) * 4);
        size_t x16_b  = align256((size_t)N * DFEAT * 2);
        size_t ov_b   = align256(((size_t)BBLK * epb + (size_t)NP * OVS_S) * 8);
        size_t sl_b   = align256((size_t)NP * BBLK * CELL_I2 * 8);
        size_t total  = ovc_b + x16_b + ov_b + sl_b;
        size_t smem_b = (size_t)NP * 128 + (size_t)(NP + 1) * 4;

        if (total <= ws_size && smem_b <= 160 * 1024) {
            char* ws = (char*)d_ws;
            int*            ovc    = (int*)ws;
            unsigned short* x16    = (unsigned short*)(ws + ovc_b);
            int2*           ovl    = (int2*)(ws + ovc_b + x16_b);
            int2*           slists = (int2*)(ws + ovc_b + x16_b + ov_b);

            int n4 = N * DFEAT / 4;
            build_conv_kernel<<<BBLK + CONV_BLK, BUILD_T, smem_b, stream>>>(
                er, ec, ev, x, x16, slists, ovc, ovl, E, NP, epb, n4);
            spmm_fused_kernel<<<NP, SPMM_T, 0, stream>>>(
                x16, x0, bias, slists, ovc, ovl, out, NP, epb);
            ov_drain_kernel<<<256, 256, 0, stream>>>(
                x, ovc, ovl, out, NP, epb);
            return;
        }
    }

    // ---- R7 single-phase path ----
    {
        size_t cur_b = align256((size_t)N * 4);
        size_t ovc_b = 256;
        size_t ov_b  = align256((size_t)E * 4);
        size_t fixed = cur_b + ovc_b + ov_b;
        int C = 0;
        if (ws_size > fixed) {
            long long cmax = (long long)((ws_size - fixed) / ((size_t)N * 8));
            for (int cand : {64, 48, 40, 32, 28, 24})
                if (cmax >= cand) { C = cand; break; }
        }
        if (C >= 24) {
            char* ws = (char*)d_ws;
            int*  cursor  = (int*)ws;
            int*  ovc     = (int*)(ws + cur_b);
            int*  ov_list = (int*)(ws + cur_b + ovc_b);
            int2* bucket  = (int2*)(ws + fixed);

            int nzero = (int)((cur_b + ovc_b) / 4);
            zero_ints_kernel<<<(nzero + 255) / 256, 256, 0, stream>>>(cursor, nzero);
            bucket_scatter_kernel<<<(E + 255) / 256, 256, 0, stream>>>(
                er, ec, ev, cursor, bucket, ovc, ov_list, E, C);
            int blocks = (N * 64 + 255) / 256;
            spmm_kernel<<<blocks, 256, 0, stream>>>(
                x, x0, bias, cursor, bucket, out, N, C);
            ov_drain_id_kernel<<<64, 256, 0, stream>>>(
                er, ec, ev, x, ovc, ov_list, out, E);
            return;
        }
    }

    // ---- last resort: atomic scatter ----
    int n4 = out_size / 4;
    init_out_kernel<<<(n4 + 255) / 256, 256, 0, stream>>>(x0, bias, out, n4);
    edge_scatter_kernel<<<8192, 256, 0, stream>>>(x, ev, er, ec, out, E);
}